// Round 2
// baseline (1603.910 us; speedup 1.0000x reference)
//
#include <hip/hip_runtime.h>
#include <stdint.h>

#define M_DIM 8192
#define N_DIM 11008
#define K_DIM 4096
#define KH    (K_DIM/2)    // 2048 int32 per weight row
#define NGRP  (K_DIM/128)  // 32 scale groups per row

#define BM 128
#define BN 128
#define BK 64

typedef float  f32x4  __attribute__((ext_vector_type(4)));
typedef short  short8 __attribute__((ext_vector_type(8)));
typedef unsigned int uint4v __attribute__((ext_vector_type(4)));
typedef int    int4v  __attribute__((ext_vector_type(4)));

// ---------- helpers ----------

__device__ __forceinline__ unsigned int pack_bf16_2(float lo, float hi) {
    // RNE f32->bf16, two values packed into one u32 (lo in low half)
    union { float f; unsigned int u; } a, b;
    a.f = lo; b.f = hi;
    unsigned int ua = a.u + 0x7FFFu + ((a.u >> 16) & 1u);
    unsigned int ub = b.u + 0x7FFFu + ((b.u >> 16) & 1u);
    return (ua >> 16) | (ub & 0xFFFF0000u);
}

typedef const unsigned int __attribute__((address_space(1)))* gas_ptr;
typedef unsigned int __attribute__((address_space(3)))* las_ptr;

__device__ __forceinline__ void gload_lds16(const unsigned short* g, unsigned short* l) {
    // async global->LDS, 16B per lane; LDS dest = wave-uniform base + lane*16
    __builtin_amdgcn_global_load_lds((gas_ptr)(uintptr_t)g, (las_ptr)(uintptr_t)l, 16, 0, 0);
}

// ---------- prepass 1: x fp32 -> bf16 ----------

__global__ __launch_bounds__(256)
void cvt_x_kernel(const float* __restrict__ x, unsigned short* __restrict__ xb, int n8) {
    int i = blockIdx.x * 256 + threadIdx.x;      // 8 elements per thread
    if (i >= n8) return;
    const f32x4* p = (const f32x4*)x + (size_t)i * 2;
    f32x4 f0 = p[0], f1 = p[1];
    uint4v o;
    o[0] = pack_bf16_2(f0[0], f0[1]);
    o[1] = pack_bf16_2(f0[2], f0[3]);
    o[2] = pack_bf16_2(f1[0], f1[1]);
    o[3] = pack_bf16_2(f1[2], f1[3]);
    *((uint4v*)xb + i) = o;
}

// ---------- prepass 2: int4 weights -> bf16 ----------

__global__ __launch_bounds__(256)
void deq_w_kernel(const int* __restrict__ wp, const float* __restrict__ sc,
                  unsigned short* __restrict__ wb, int n4) {
    int i = blockIdx.x * 256 + threadIdx.x;      // 4 int32 -> 8 bf16 per thread
    if (i >= n4) return;
    int i32  = i << 2;                           // int32 linear index
    int row  = i32 >> 11;                        // / 2048
    int i2   = i32 & 2047;
    float scale = sc[row * NGRP + (i2 >> 6)];    // group = (2*i2)/128 = i2/64
    int4v v = *((const int4v*)wp + i);
    uint4v o;
#pragma unroll
    for (int j = 0; j < 4; ++j) {
        float lo = (float)((v[j] & 15) - 8) * scale;
        float hi = (float)(((v[j] >> 4) & 15) - 8) * scale;
        o[j] = pack_bf16_2(lo, hi);              // even col = low nibble, odd = high
    }
    *((uint4v*)wb + i) = o;
}

// ---------- main GEMM: out[m][n] = sum_k A[m][k]*B[n][k] + bias[n] ----------
// m97 structure: 128x128 tile, BK=64, 4 waves, global_load_lds staging,
// 16x16x32 bf16 MFMA, 4x4 acc fragments per wave.

__global__ __launch_bounds__(256)
void gemm_bf16_kernel(const unsigned short* __restrict__ A,   // [M][K] bf16
                      const unsigned short* __restrict__ B,   // [N][K] bf16
                      const float* __restrict__ bias,
                      float* __restrict__ out) {
    __shared__ unsigned short ldsA[BM * BK];
    __shared__ unsigned short ldsB[BN * BK];

    const int tid  = (int)threadIdx.x;
    const int lane = tid & 63;
    const int wid  = tid >> 6;
    const int m0   = (int)blockIdx.y * BM;
    const int n0   = (int)blockIdx.x * BN;

    // staging: wave wid covers rows [wid*32, wid*32+32), 4 chunks of 8 rows (1KB each)
    const int srow = wid * 32 + (lane >> 3);
    const int scol = (lane & 7) * 8;
    const unsigned short* gA = A + (size_t)(m0 + srow) * K_DIM + scol;
    const unsigned short* gB = B + (size_t)(n0 + srow) * K_DIM + scol;
    unsigned short* lA = &ldsA[(wid * 32) * BK];   // wave-uniform LDS base
    unsigned short* lB = &ldsB[(wid * 32) * BK];

    // fragment addressing (16x16x32: lane holds row=lane&15, k=(lane>>4)*8 ..+8)
    const int lr = lane & 15;
    const int lk = (lane >> 4) * 8;
    const int wm = (wid >> 1) * 64;    // wave's 64x64 output quadrant
    const int wn = (wid & 1) * 64;
    const unsigned short* fA = &ldsA[(wm + lr) * BK + lk];
    const unsigned short* fB = &ldsB[(wn + lr) * BK + lk];

    f32x4 acc[4][4];
#pragma unroll
    for (int i = 0; i < 4; ++i)
#pragma unroll
        for (int j = 0; j < 4; ++j) acc[i][j] = (f32x4){0.f, 0.f, 0.f, 0.f};

    for (int t = 0; t < K_DIM / BK; ++t) {
        __syncthreads();                       // all reads of LDS from prev iter done
        const unsigned short* ga = gA + t * BK;
        const unsigned short* gb = gB + t * BK;
#pragma unroll
        for (int c = 0; c < 4; ++c) {
            gload_lds16(ga + (size_t)(c * 8) * K_DIM, lA + (c * 8) * BK);
            gload_lds16(gb + (size_t)(c * 8) * K_DIM, lB + (c * 8) * BK);
        }
        __syncthreads();                       // compiler drains vmcnt before barrier

#pragma unroll
        for (int kk = 0; kk < 2; ++kk) {
            short8 a[4], b[4];
#pragma unroll
            for (int mi = 0; mi < 4; ++mi)
                a[mi] = *(const short8*)&fA[(mi * 16) * BK + kk * 32];
#pragma unroll
            for (int ni = 0; ni < 4; ++ni)
                b[ni] = *(const short8*)&fB[(ni * 16) * BK + kk * 32];
#pragma unroll
            for (int mi = 0; mi < 4; ++mi)
#pragma unroll
                for (int ni = 0; ni < 4; ++ni)
                    acc[mi][ni] = __builtin_amdgcn_mfma_f32_16x16x32_bf16(
                        a[mi], b[ni], acc[mi][ni], 0, 0, 0);
        }
    }

    // epilogue: C/D layout col=lane&15, row=(lane>>4)*4+r
#pragma unroll
    for (int ni = 0; ni < 4; ++ni) {
        const int col = n0 + wn + ni * 16 + lr;
        const float bv = bias[col];
#pragma unroll
        for (int mi = 0; mi < 4; ++mi) {
            const int rbase = m0 + wm + mi * 16 + (lane >> 4) * 4;
#pragma unroll
            for (int r = 0; r < 4; ++r)
                out[(size_t)(rbase + r) * N_DIM + col] = acc[mi][ni][r] + bv;
        }
    }
}

// ---------- fallback (only if workspace too small): simple fp32 tiled ----------

__global__ __launch_bounds__(256)
void fallback_kernel(const float* __restrict__ x, const int* __restrict__ wp,
                     const float* __restrict__ sc, const float* __restrict__ bias,
                     float* __restrict__ out) {
    __shared__ float xs[16][128];
    __shared__ float wsh[16][129];
    const int tid = (int)threadIdx.x;
    const int tx = tid & 15;   // n within tile
    const int ty = tid >> 4;   // m within tile
    const int m0 = (int)blockIdx.y * 16;
    const int n0 = (int)blockIdx.x * 16;
    float acc = 0.f;
    for (int g = 0; g < NGRP; ++g) {
        __syncthreads();
        {   // stage x: 16 rows x 128, 8 floats/thread
            const float* p = x + (size_t)(m0 + ty) * K_DIM + g * 128 + tx * 8;
#pragma unroll
            for (int j = 0; j < 8; ++j) xs[ty][tx * 8 + j] = p[j];
        }
        {   // stage + dequant w: 16 rows x 64 int32 -> 128 floats
            const int* p = wp + (size_t)(n0 + ty) * KH + g * 64 + tx * 4;
            float scale = sc[(n0 + ty) * NGRP + g];
#pragma unroll
            for (int j = 0; j < 4; ++j) {
                int v = p[j];
                wsh[ty][tx * 8 + 2 * j]     = (float)((v & 15) - 8) * scale;
                wsh[ty][tx * 8 + 2 * j + 1] = (float)(((v >> 4) & 15) - 8) * scale;
            }
        }
        __syncthreads();
#pragma unroll 16
        for (int k = 0; k < 128; ++k) acc += xs[ty][k] * wsh[tx][k];
    }
    out[(size_t)(m0 + ty) * N_DIM + n0 + tx] = acc + bias[n0 + tx];
}

// ---------- launcher ----------

extern "C" void kernel_launch(void* const* d_in, const int* in_sizes, int n_in,
                              void* d_out, int out_size, void* d_ws, size_t ws_size,
                              hipStream_t stream) {
    const float* x    = (const float*)d_in[0];
    const int*   wp   = (const int*)d_in[1];
    const float* sc   = (const float*)d_in[2];
    const float* bias = (const float*)d_in[3];
    float* out = (float*)d_out;

    const size_t xb_bytes = (size_t)M_DIM * K_DIM * 2;   // 67,108,864
    const size_t wb_bytes = (size_t)N_DIM * K_DIM * 2;   // 90,177,536

    if (ws_size >= xb_bytes + wb_bytes) {
        unsigned short* xb = (unsigned short*)d_ws;
        unsigned short* wb = (unsigned short*)((char*)d_ws + xb_bytes);
        {
            int n8 = M_DIM * K_DIM / 8;
            cvt_x_kernel<<<n8 / 256, 256, 0, stream>>>(x, xb, n8);
        }
        {
            int n4 = N_DIM * KH / 4;
            deq_w_kernel<<<n4 / 256, 256, 0, stream>>>(wp, sc, wb, n4);
        }
        dim3 grid(N_DIM / BN, M_DIM / BM);
        gemm_bf16_kernel<<<grid, 256, 0, stream>>>(xb, wb, bias, out);
    } else {
        dim3 grid(N_DIM / 16, M_DIM / 16);
        fallback_kernel<<<grid, 256, 0, stream>>>(x, wp, sc, bias, out);
    }
}

// Round 4
// 1148.222 us; speedup vs baseline: 1.3969x; 1.3969x over previous
//
#include <hip/hip_runtime.h>
#include <stdint.h>

#define M_DIM 8192
#define N_DIM 11008
#define K_DIM 4096
#define KH    (K_DIM/2)    // 2048 int32 per weight row
#define NGRP  (K_DIM/128)  // 32 scale groups per row

// ---- 256x256 deep-pipelined GEMM geometry ----
#define BM 256
#define BN 256
#define BK 32
#define NT (K_DIM/BK)        // 128 K-tiles
#define SLOT_ELEMS 16384     // one K-tile: A 256x32 + B 256x32 bf16 elements
#define SEC_B 8192           // B section offset within a slot (elements)

typedef float  f32x4  __attribute__((ext_vector_type(4)));
typedef short  short8 __attribute__((ext_vector_type(8)));
typedef unsigned int uint4v __attribute__((ext_vector_type(4)));
typedef int    int4v  __attribute__((ext_vector_type(4)));

#define VMWAIT(N) asm volatile("s_waitcnt vmcnt(" #N ")" ::: "memory")
#define BARRIER() do { asm volatile("" ::: "memory"); \
                       __builtin_amdgcn_s_barrier();  \
                       asm volatile("" ::: "memory"); } while (0)

// ---------- helpers ----------

__device__ __forceinline__ unsigned int pack_bf16_2(float lo, float hi) {
    union { float f; unsigned int u; } a, b;
    a.f = lo; b.f = hi;
    unsigned int ua = a.u + 0x7FFFu + ((a.u >> 16) & 1u);
    unsigned int ub = b.u + 0x7FFFu + ((b.u >> 16) & 1u);
    return (ua >> 16) | (ub & 0xFFFF0000u);
}

typedef const unsigned int __attribute__((address_space(1)))* gas_ptr;
typedef unsigned int __attribute__((address_space(3)))* las_ptr;

__device__ __forceinline__ void gload_lds16(const unsigned short* g, unsigned short* l) {
    // async global->LDS: LDS dest = wave-uniform base + lane*16B; global src is per-lane
    __builtin_amdgcn_global_load_lds((gas_ptr)(uintptr_t)g, (las_ptr)(uintptr_t)l, 16, 0, 0);
}

// ---------- prepass 1: x fp32 -> bf16 ----------

__global__ __launch_bounds__(256)
void cvt_x_kernel(const float* __restrict__ x, unsigned short* __restrict__ xb, int n8) {
    int i = blockIdx.x * 256 + threadIdx.x;      // 8 elements per thread
    if (i >= n8) return;
    const f32x4* p = (const f32x4*)x + (size_t)i * 2;
    f32x4 f0 = p[0], f1 = p[1];
    uint4v o;
    o[0] = pack_bf16_2(f0[0], f0[1]);
    o[1] = pack_bf16_2(f0[2], f0[3]);
    o[2] = pack_bf16_2(f1[0], f1[1]);
    o[3] = pack_bf16_2(f1[2], f1[3]);
    *((uint4v*)xb + i) = o;
}

// ---------- prepass 2: int4 weights -> bf16 ----------

__global__ __launch_bounds__(256)
void deq_w_kernel(const int* __restrict__ wp, const float* __restrict__ sc,
                  unsigned short* __restrict__ wb, int n4) {
    int i = blockIdx.x * 256 + threadIdx.x;      // 4 int32 -> 8 bf16 per thread
    if (i >= n4) return;
    int i32  = i << 2;
    int row  = i32 >> 11;                        // / 2048
    int i2   = i32 & 2047;
    float scale = sc[row * NGRP + (i2 >> 6)];
    int4v v = *((const int4v*)wp + i);
    uint4v o;
#pragma unroll
    for (int j = 0; j < 4; ++j) {
        float lo = (float)((v[j] & 15) - 8) * scale;
        float hi = (float)(((v[j] >> 4) & 15) - 8) * scale;
        o[j] = pack_bf16_2(lo, hi);
    }
    *((uint4v*)wb + i) = o;
}

// ---------- main GEMM: 256x256 tile, BK=32, ring-4 LDS, counted vmcnt ----------
// out[m][n] = sum_k A[m][k]*B[n][k] + bias[n]
// 8 waves (2M x 4N), per-wave 128x64 output = 8x4 16x16 fragments.
// LDS: 4 slots x (A 256x32 | B 256x32) bf16 = 128 KiB, prefetch depth 3.
// T2: source pre-swizzle chunk c=(l&3)^((l>>3)&3); read chunk p=g^((lr>>1)&3)
//     -> 2 addr/bank per 16-lane phase (free) instead of 8-16-way.
// Invariant: slot staged at step t is read at t+3 (landing proven by per-wave
// vmcnt(8) + barrier) and re-staged at t+4 (after end-of-(t+3) barrier, all
// waves' ds_reads drained by their lgkm waits before that barrier).

__global__ __launch_bounds__(512)
void gemm_bf16_256(const unsigned short* __restrict__ A,   // [M][K] bf16
                   const unsigned short* __restrict__ B,   // [N][K] bf16
                   const float* __restrict__ bias,
                   float* __restrict__ out) {
    __shared__ unsigned short lds[4 * SLOT_ELEMS];         // 128 KiB

    const int tid  = (int)threadIdx.x;
    const int lane = tid & 63;
    const int wid  = tid >> 6;          // 0..7
    const int wr   = wid >> 2;          // 0..1  M-half of wave
    const int wc   = wid & 3;           // 0..3  N-quarter of wave

    // block -> tile mapping: XCD-chunked (1376 blocks = 8 XCDs x 172),
    // each XCD covers 4 contiguous m-rows x all 43 n-cols (A L2-resident)
    int bid = (int)blockIdx.x;
    int swz = (bid & 7) * 172 + (bid >> 3);
    int bm  = swz / 43;
    int bn  = swz - bm * 43;
    const int m0 = bm * BM;
    const int n0 = bn * BN;

    // ---- staging setup: waves 0-3 stage A-tile, waves 4-7 stage B-tile ----
    const int sec = wid >> 2;                         // 0=A, 1=B
    const int w4  = wid & 3;
    const int c   = (lane & 3) ^ ((lane >> 3) & 3);   // pre-swizzled source chunk
    const unsigned short* __restrict__ Gw =
        (sec == 0) ? (A + (size_t)m0 * K_DIM) : (B + (size_t)n0 * K_DIM);
    int srcoff[4];
#pragma unroll
    for (int i = 0; i < 4; ++i)
        srcoff[i] = (w4 * 64 + i * 16 + (lane >> 2)) * K_DIM + c * 8;
    const int ldst_base = sec * SEC_B + w4 * 2048;    // wave-uniform (elements)

    // ---- fragment read offsets (swizzled) ----
    const int lr = lane & 15;
    const int g  = lane >> 4;
    const int p  = g ^ ((lr >> 1) & 3);
    const int aoff = (wr * 128 + lr) * BK + p * 8;
    const int boff = SEC_B + (wc * 64 + lr) * BK + p * 8;

    f32x4 acc[8][4];
#pragma unroll
    for (int mi = 0; mi < 8; ++mi)
#pragma unroll
        for (int ni = 0; ni < 4; ++ni) acc[mi][ni] = (f32x4){0.f, 0.f, 0.f, 0.f};

    // ---- prologue: stage tiles 0..2 into slots 0..2 ----
#pragma unroll
    for (int s = 0; s < 3; ++s)
#pragma unroll
        for (int i = 0; i < 4; ++i)
            gload_lds16(Gw + srcoff[i] + s * BK,
                        lds + s * SLOT_ELEMS + ldst_base + i * 512);
    VMWAIT(8);        // tile 0 landed (this wave's 4 loads); barrier publishes all waves'
    BARRIER();

#pragma unroll 4
    for (int t = 0; t < NT; ++t) {
        const int slot = t & 3;
        const unsigned short* sl = lds + slot * SLOT_ELEMS;

        short8 af[8], bf[4];
#pragma unroll
        for (int mi = 0; mi < 8; ++mi)
            af[mi] = *(const short8*)(sl + aoff + mi * 512);
#pragma unroll
        for (int ni = 0; ni < 4; ++ni)
            bf[ni] = *(const short8*)(sl + boff + ni * 512);

        // stage tile t+3 (clamped dummy re-stage at tail keeps vmcnt uniform)
        const int kt = (t + 3 < NT) ? (t + 3) : (NT - 1);
        unsigned short* dsl = lds + ((t + 3) & 3) * SLOT_ELEMS + ldst_base;
#pragma unroll
        for (int i = 0; i < 4; ++i)
            gload_lds16(Gw + srcoff[i] + kt * BK, dsl + i * 512);

        __builtin_amdgcn_s_setprio(1);
#pragma unroll
        for (int mi = 0; mi < 8; ++mi)
#pragma unroll
            for (int ni = 0; ni < 4; ++ni)
                acc[mi][ni] = __builtin_amdgcn_mfma_f32_16x16x32_bf16(
                    af[mi], bf[ni], acc[mi][ni], 0, 0, 0);
        __builtin_amdgcn_s_setprio(0);

        VMWAIT(8);    // keep 2 tiles (8 loads) in flight; tile t+1 landed
        BARRIER();
    }

    VMWAIT(0);        // drain in-flight LDS-DMA before epilogue/endpgm
                      // (stale writes must not land in a successor block's LDS)

    // ---- epilogue: C layout col=lane&15, row=(lane>>4)*4+r ----
#pragma unroll
    for (int ni = 0; ni < 4; ++ni) {
        const int col = n0 + wc * 64 + ni * 16 + lr;
        const float bv = bias[col];
#pragma unroll
        for (int mi = 0; mi < 8; ++mi) {
            const int rbase = m0 + wr * 128 + mi * 16 + g * 4;
#pragma unroll
            for (int r = 0; r < 4; ++r)
                out[(size_t)(rbase + r) * N_DIM + col] = acc[mi][ni][r] + bv;
        }
    }
}

// ---------- fallback (only if workspace too small): simple fp32 tiled ----------

__global__ __launch_bounds__(256)
void fallback_kernel(const float* __restrict__ x, const int* __restrict__ wp,
                     const float* __restrict__ sc, const float* __restrict__ bias,
                     float* __restrict__ out) {
    __shared__ float xs[16][128];
    __shared__ float wsh[16][129];
    const int tid = (int)threadIdx.x;
    const int tx = tid & 15;
    const int ty = tid >> 4;
    const int m0 = (int)blockIdx.y * 16;
    const int n0 = (int)blockIdx.x * 16;
    float acc = 0.f;
    for (int gg = 0; gg < NGRP; ++gg) {
        __syncthreads();
        {
            const float* pp = x + (size_t)(m0 + ty) * K_DIM + gg * 128 + tx * 8;
#pragma unroll
            for (int j = 0; j < 8; ++j) xs[ty][tx * 8 + j] = pp[j];
        }
        {
            const int* pp = wp + (size_t)(n0 + ty) * KH + gg * 64 + tx * 4;
            float scale = sc[(n0 + ty) * NGRP + gg];
#pragma unroll
            for (int j = 0; j < 4; ++j) {
                int v = pp[j];
                wsh[ty][tx * 8 + 2 * j]     = (float)((v & 15) - 8) * scale;
                wsh[ty][tx * 8 + 2 * j + 1] = (float)(((v >> 4) & 15) - 8) * scale;
            }
        }
        __syncthreads();
#pragma unroll 16
        for (int k = 0; k < 128; ++k) acc += xs[ty][k] * wsh[tx][k];
    }
    out[(size_t)(m0 + ty) * N_DIM + n0 + tx] = acc + bias[n0 + tx];
}

// ---------- launcher ----------

extern "C" void kernel_launch(void* const* d_in, const int* in_sizes, int n_in,
                              void* d_out, int out_size, void* d_ws, size_t ws_size,
                              hipStream_t stream) {
    const float* x    = (const float*)d_in[0];
    const int*   wp   = (const int*)d_in[1];
    const float* sc   = (const float*)d_in[2];
    const float* bias = (const float*)d_in[3];
    float* out = (float*)d_out;

    const size_t xb_bytes = (size_t)M_DIM * K_DIM * 2;   // 64 MiB
    const size_t wb_bytes = (size_t)N_DIM * K_DIM * 2;   // 86 MiB

    if (ws_size >= xb_bytes + wb_bytes) {
        unsigned short* xb = (unsigned short*)d_ws;
        unsigned short* wb = (unsigned short*)((char*)d_ws + xb_bytes);
        {
            int n8 = M_DIM * K_DIM / 8;
            cvt_x_kernel<<<n8 / 256, 256, 0, stream>>>(x, xb, n8);
        }
        {
            int n4 = N_DIM * KH / 4;
            deq_w_kernel<<<n4 / 256, 256, 0, stream>>>(wp, sc, wb, n4);
        }
        dim3 grid((N_DIM / BN) * (M_DIM / BM));   // 43*32 = 1376 = 8*172
        gemm_bf16_256<<<grid, 512, 0, stream>>>(xb, wb, bias, out);
    } else {
        dim3 grid(N_DIM / 16, M_DIM / 16);
        fallback_kernel<<<grid, 256, 0, stream>>>(x, wp, sc, bias, out);
    }
}